// Round 4
// baseline (269.889 us; speedup 1.0000x reference)
//
#include <hip/hip_runtime.h>

// CBC (classification-by-components) fused kernel, v3 (2nd resubmit — broker flake;
// kernel audited: terminates, memory-safe, no container-killing constructs).
// x:[B,1024] f32, components:[5,1024] f32, reasonings:[5,3,2] f32 -> probs:[B,3] f32.
//
// v1 structure (one 64-lane wave per row, full-wave-coalesced 1KB loads,
// diff-form d^2, butterfly reduce) with the occupancy fixed:
//  - components in LDS (20 KB/block) instead of 80 VGPRs
//  - per-lane reasoning params (7 regs, only class c = lane) instead of 21
//  - __launch_bounds__(256, 8): force VGPR <= 64 -> 8 waves/SIMD = 32 waves/CU
//    (8 blocks x 20 KB = 160 KiB LDS, exactly the CU budget)
//  - 2048 blocks: 8192 waves resident = full machine, 4 rows/wave grid-stride
// Rationale: per-row serial tail (30 shuffles + exp + store) is hidden by TLP,
// not per-wave ILP; v2 proved deep ILP + low occupancy loses.

#define DD 1024
#define KK 5
#define CC 3
#define F4R (DD / 4)          // 256 float4 per row
#define JN (F4R / 64)         // 4 j-steps per lane

__global__ __launch_bounds__(256, 8) void cbc_kernel(
    const float* __restrict__ x,
    const float* __restrict__ comps,
    const float* __restrict__ reas,
    float* __restrict__ out,
    int B)
{
    __shared__ float4 cl[KK * F4R];   // 20480 B

    const int tid  = threadIdx.x;
    const int lane = tid & 63;
    const int waves_per_block = blockDim.x >> 6;
    const int wave    = blockIdx.x * waves_per_block + (tid >> 6);
    const int n_waves = gridDim.x * waves_per_block;

    // ---- stage components into LDS (coalesced float4; 5 thread-iters) ----
    const float4* c4 = (const float4*)comps;
    for (int i = tid; i < KK * F4R; i += blockDim.x) cl[i] = c4[i];

    // ---- per-lane reasoning params for class c = lane (lanes >= 3 dummy) ----
    // pk = A; nk = (1-A)*B; w = pk-nk; bias = sum nk; invden = 1/sum(pk+nk)
    const int c = (lane < CC) ? lane : 0;
    float wv[KK], bias = 0.f, den = 0.f;
#pragma unroll
    for (int k = 0; k < KK; ++k) {
        float a = reas[k * (CC * 2) + c * 2 + 0];
        float b = reas[k * (CC * 2) + c * 2 + 1];
        a = fminf(fmaxf(a, 0.f), 1.f);
        b = fminf(fmaxf(b, 0.f), 1.f);
        float nk = (1.f - a) * b;
        wv[k] = a - nk;
        bias += nk;
        den  += a + nk;
    }
    const float invden = 1.f / den;

    __syncthreads();

    const float4* x4 = (const float4*)x;

    for (int row = wave; row < B; row += n_waves) {
        // ---- load this row: 4 x dwordx4 per lane, 1KB contiguous per instr ----
        float4 xv[JN];
        const float4* p = x4 + (size_t)row * F4R + lane;
#pragma unroll
        for (int j = 0; j < JN; ++j) xv[j] = p[j * 64];

        // ---- d^2 partials (diff form: no clamp needed, exact vs reference) ----
        float acc[KK];
#pragma unroll
        for (int k = 0; k < KK; ++k) acc[k] = 0.f;

#pragma unroll
        for (int j = 0; j < JN; ++j) {
#pragma unroll
            for (int k = 0; k < KK; ++k) {
                float4 cv = cl[k * F4R + j * 64 + lane];
                float dx = xv[j].x - cv.x;
                float dy = xv[j].y - cv.y;
                float dz = xv[j].z - cv.z;
                float dw = xv[j].w - cv.w;
                acc[k] += dx * dx;
                acc[k] += dy * dy;
                acc[k] += dz * dz;
                acc[k] += dw * dw;
            }
        }

        // ---- 64-lane butterfly: all lanes end with full d2[k] ----
#pragma unroll
        for (int k = 0; k < KK; ++k) {
#pragma unroll
            for (int off = 32; off > 0; off >>= 1)
                acc[k] += __shfl_xor(acc[k], off, 64);
        }

        // ---- epilogue: lanes 0..2 write this row's 3 class probs ----
        if (lane < CC) {
            float num = bias;
#pragma unroll
            for (int k = 0; k < KK; ++k)
                num += __expf(-0.5f * acc[k]) * wv[k];   // variance = 1
            out[(size_t)row * CC + lane] = num * invden;
        }
    }
}

extern "C" void kernel_launch(void* const* d_in, const int* in_sizes, int n_in,
                              void* d_out, int out_size, void* d_ws, size_t ws_size,
                              hipStream_t stream) {
    const float* x = (const float*)d_in[0];
    const float* comps = (const float*)d_in[1];
    const float* reas = (const float*)d_in[2];
    float* out = (float*)d_out;
    const int B = in_sizes[0] / DD;   // 32768 rows

    // 2048 blocks x 256 threads = 8192 waves (full residency at 32 waves/CU),
    // 4 rows per wave grid-stride.
    const int blocks = 2048;
    cbc_kernel<<<blocks, 256, 0, stream>>>(x, comps, reas, out, B);
}

// Round 5
// 193.224 us; speedup vs baseline: 1.3968x; 1.3968x over previous
//
#include <hip/hip_runtime.h>

// CBC (classification-by-components) fused kernel, v4.
// x:[B,1024] f32, components:[5,1024] f32, reasonings:[5,3,2] f32 -> probs:[B,3] f32.
//
// v3 post-mortem: __launch_bounds__(256,8) drove the allocator to 32 VGPRs and
// spilled xv[4] to scratch -> +248 MB of HBM traffic (WRITE_SIZE 124 MB, FETCH
// 286 MB), kernel 140 us. Fix:
//  - __launch_bounds__(256, 4): <=128 VGPR budget, guaranteed spill-free.
//    Natural demand ~50 regs; if the allocator lands <=64 the HW still runs
//    8 waves/SIMD (LDS = 20 KB/block allows exactly 8 blocks/CU = 160 KiB).
//  - xv loaded inline per j-step (no mandatory 16-reg array); compiler
//    pipelines the 4 loads as budget allows instead of being forced to.
//  - everything else as v3: components in LDS, 7-reg reasoning state,
//    one wave per row, full-wave-coalesced 1KB dwordx4 loads, diff-form d^2,
//    64-lane butterfly, lanes 0..2 store the 3 class probs.

#define DD 1024
#define KK 5
#define CC 3
#define F4R (DD / 4)          // 256 float4 per row
#define JN (F4R / 64)         // 4 j-steps per lane

__global__ __launch_bounds__(256, 4) void cbc_kernel(
    const float* __restrict__ x,
    const float* __restrict__ comps,
    const float* __restrict__ reas,
    float* __restrict__ out,
    int B)
{
    __shared__ float4 cl[KK * F4R];   // 20480 B

    const int tid  = threadIdx.x;
    const int lane = tid & 63;
    const int waves_per_block = blockDim.x >> 6;
    const int wave    = blockIdx.x * waves_per_block + (tid >> 6);
    const int n_waves = gridDim.x * waves_per_block;

    // ---- stage components into LDS (coalesced float4; 5 iters/thread) ----
    const float4* c4 = (const float4*)comps;
    for (int i = tid; i < KK * F4R; i += blockDim.x) cl[i] = c4[i];

    // ---- per-lane reasoning params for class c = lane (lanes >= 3 dummy) ----
    // pk = A; nk = (1-A)*B; w = pk-nk; bias = sum nk; invden = 1/sum(pk+nk)
    const int c = (lane < CC) ? lane : 0;
    float wv[KK], bias = 0.f, den = 0.f;
#pragma unroll
    for (int k = 0; k < KK; ++k) {
        float a = reas[k * (CC * 2) + c * 2 + 0];
        float b = reas[k * (CC * 2) + c * 2 + 1];
        a = fminf(fmaxf(a, 0.f), 1.f);
        b = fminf(fmaxf(b, 0.f), 1.f);
        float nk = (1.f - a) * b;
        wv[k] = a - nk;
        bias += nk;
        den  += a + nk;
    }
    const float invden = 1.f / den;

    __syncthreads();

    const float4* x4 = (const float4*)x;

    for (int row = wave; row < B; row += n_waves) {
        const float4* p = x4 + (size_t)row * F4R + lane;

        float acc[KK];
#pragma unroll
        for (int k = 0; k < KK; ++k) acc[k] = 0.f;

        // ---- d^2 partials (diff form); xv loaded inline, compiler pipelines ----
#pragma unroll
        for (int j = 0; j < JN; ++j) {
            float4 xv = p[j * 64];
#pragma unroll
            for (int k = 0; k < KK; ++k) {
                float4 cv = cl[k * F4R + j * 64 + lane];
                float dx = xv.x - cv.x;
                float dy = xv.y - cv.y;
                float dz = xv.z - cv.z;
                float dw = xv.w - cv.w;
                acc[k] += dx * dx;
                acc[k] += dy * dy;
                acc[k] += dz * dz;
                acc[k] += dw * dw;
            }
        }

        // ---- 64-lane butterfly: all lanes end with full d2[k] ----
#pragma unroll
        for (int k = 0; k < KK; ++k) {
#pragma unroll
            for (int off = 32; off > 0; off >>= 1)
                acc[k] += __shfl_xor(acc[k], off, 64);
        }

        // ---- epilogue: lanes 0..2 write this row's 3 class probs ----
        if (lane < CC) {
            float num = bias;
#pragma unroll
            for (int k = 0; k < KK; ++k)
                num += __expf(-0.5f * acc[k]) * wv[k];   // variance = 1
            out[(size_t)row * CC + lane] = num * invden;
        }
    }
}

extern "C" void kernel_launch(void* const* d_in, const int* in_sizes, int n_in,
                              void* d_out, int out_size, void* d_ws, size_t ws_size,
                              hipStream_t stream) {
    const float* x = (const float*)d_in[0];
    const float* comps = (const float*)d_in[1];
    const float* reas = (const float*)d_in[2];
    float* out = (float*)d_out;
    const int B = in_sizes[0] / DD;   // 32768 rows

    // 2048 blocks x 256 threads = 8192 waves, 4 rows/wave grid-stride.
    // (If VGPR <= 64: 8 blocks/CU resident = full machine in one shot.)
    const int blocks = 2048;
    cbc_kernel<<<blocks, 256, 0, stream>>>(x, comps, reas, out, B);
}